// Round 12
// baseline (110.666 us; speedup 1.0000x reference)
//
#include <hip/hip_runtime.h>
#include <hip/hip_bf16.h>

// Glow coupling layer, fused. rows N = 262144, C = 64.
// r2 = MLP_s2(x2); y1 = e(s2)*x1 + t2; r1 = MLP_s1(y1); y2 = e(s1)*x2 + t1.
//
// Round 12 = R10 structure with 32-ROW BLOCKS (was 64):
//   LDS 16KB (A/B regions 8KB) -> 8 blocks/CU (wave-slot capped), 32 waves/CU
//   = 2x R10's parallelism; grid 8192. LB(256,8) (VGPR cap 64; R10/R11 used
//   48-56 for identical code). All R10 pieces kept: region-swap 6-barrier
//   plan, per-layer JIT weight loads + sched_barrier(0), h [32][256B] XOR
//   (r&7)<<4, planes [32][80B], in-lane epilogue via W3 interleave, early
//   epilogue x-loads. Spill tripwire: WRITE_SIZE must stay 65536 KB.
//
// MFMA v_mfma_f32_16x16x32_bf16, W = A-operand, activations = B-operand:
//   A frag: lane l holds A[row=l&15][k=(l>>4)*8+j]
//   B frag: lane l holds B[k=(l>>4)*8+j][col=l&15]
//   D     : lane l reg i -> (A-row = 4*(l>>4)+i, col = l&15)  [m89/m91]

using bf16x8 = __attribute__((ext_vector_type(8))) short;
using f32x4  = __attribute__((ext_vector_type(4))) float;
using u32x2  = __attribute__((ext_vector_type(2))) unsigned int;

__device__ __forceinline__ unsigned short f2bf(float f) {
    unsigned int u = __float_as_uint(f);
    u += 0x7FFFu + ((u >> 16) & 1u);
    return (unsigned short)(u >> 16);
}
__device__ __forceinline__ unsigned int pk2bf(float a, float b) {
    union { __hip_bfloat162 h; unsigned int u; } cv;
    cv.h = __float22bfloat162_rn(float2{a, b});
    return cv.u;   // low16 = bf16(a), high16 = bf16(b)
}
__device__ __forceinline__ float lo16f(unsigned int u) { return __uint_as_float(u << 16); }
__device__ __forceinline__ float hi16f(unsigned int u) { return __uint_as_float(u & 0xFFFF0000u); }

__device__ __forceinline__ f32x4 mfma16(bf16x8 a, bf16x8 b, f32x4 c) {
    return __builtin_amdgcn_mfma_f32_16x16x32_bf16(a, b, c, 0, 0, 0);
}

// e(s) = exp(3.18*atan(s/5)) = exp2(4.5877702*atan(0.2 s)); deg-11 minimax.
__device__ __forceinline__ float e_fun(float s) {
    float z = 0.2f * s;
    float a = fabsf(z);
    float t = fminf(a, __builtin_amdgcn_rcpf(a));   // a<=1 ? a : 1/a
    float u = t * t;
    float p = -0.0537741f;
    p = fmaf(p, u,  0.2415614f);
    p = fmaf(p, u, -0.5341673f);
    p = fmaf(p, u,  0.8879339f);
    p = fmaf(p, u, -1.5260000f);
    p = fmaf(p, u,  4.5876659f);
    p = p * t;
    float r = (a > 1.0f) ? (7.2064613f - p) : p;    // K*pi/2 - p
    r = copysignf(r, s);
    return __builtin_amdgcn_exp2f(r);
}

// W3 interleaved permutation: wave w, frag-row fr = 4q+i ->
//   i<2: s-feature 8w+2q+i ; i>=2: t-feature 32+8w+2q+(i-2)
__device__ __forceinline__ int feat3b(int w, int fr) {
    int q = fr >> 2, i = fr & 3;
    int base = 8 * w + 2 * q;
    return (i < 2) ? (base + i) : (32 + base + (i - 2));
}

// LDS: region A [32][256B] @0 (8192); region B [32][256B] @8192.
// planes (hi [32][80B] + lo [32][80B]) time-share the first 5120B of a region.
#define LDS_BYTES 16384

#define BIAS_OFF 114688           // 112 tiles * 1024B
#define WS_NEED  (114688 + 2560)

struct WPtrs { const float *w1, *b1, *w2, *b2, *w3, *b3; };

__device__ __forceinline__ bf16x8 load_wfrag(const float* __restrict__ W, int K, int frow, int k0) {
    const float4* p = reinterpret_cast<const float4*>(W + (size_t)frow * K + k0);
    float4 a = p[0], b = p[1];
    bf16x8 r;
    r[0] = (short)f2bf(a.x); r[1] = (short)f2bf(a.y);
    r[2] = (short)f2bf(a.z); r[3] = (short)f2bf(a.w);
    r[4] = (short)f2bf(b.x); r[5] = (short)f2bf(b.y);
    r[6] = (short)f2bf(b.z); r[7] = (short)f2bf(b.w);
    return r;
}

template<int MODE>
__device__ __forceinline__ bf16x8 get_frag(const char* wsb, const WPtrs& P, int mlp,
                                           int tile, int which, int row, int k0, int lane) {
    if constexpr (MODE != 0) {
        union { uint4 q; bf16x8 v; } u;
        u.q = reinterpret_cast<const uint4*>(wsb)[(mlp * 56 + tile) * 64 + lane];
        return u.v;
    } else {
        const float* W = (which == 0) ? P.w1 : (which == 1) ? P.w2 : P.w3;
        return load_wfrag(W, (which == 0) ? 32 : 128, row, k0);
    }
}

__device__ __forceinline__ f32x4 ld4(const float* p) {
    return *reinterpret_cast<const f32x4*>(p);
}

// ---- one 3-layer MLP over the 32-row tile, 4-wave f-split ----
// L1 input from planes ph/pl ([32][80B] hi/lo bf16).
// PRE=1: issue 2 float2 x-loads (gpre) before the L3 loop, return in xv.
// rr[m] regs: i<2 -> s at col 8w+2lg+i ; i>=2 -> t at col 8w+2lg+(i-2).
template<int MODE, int PRE>
__device__ __forceinline__ void run_mlp(
    const char* __restrict__ wsb, const WPtrs& P, int mlp,
    const char* __restrict__ ph, const char* __restrict__ pl,
    char* __restrict__ h1, char* __restrict__ h2,
    const float* __restrict__ gpre, float2 (&xv)[2],
    int w, int lg, int lr, int lane, f32x4 (&rr)[2])
{
    const int sw = (lr & 7) << 4;
    const float* bias = reinterpret_cast<const float*>(wsb + BIAS_OFF) + mlp * 320;

    // precomputed LDS slots (loop-invariant)
    int rslot[4];
    #pragma unroll
    for (int ks = 0; ks < 4; ++ks) rslot[ks] = (64 * ks + 16 * lg) ^ sw;
    const int wslot0 = (32 * (2 * w + 0) + 8 * lg) ^ sw;
    const int wslot1 = (32 * (2 * w + 1) + 8 * lg) ^ sw;
    const int pbase  = lr * 80 + 16 * lg;   // plane-read base (row lr)

    // ---------- layer 1: K=32 (hi+lo), wave's tiles ft = 2w, 2w+1 ----------
    bf16x8 wb1[2]; f32x4 b1v[2];
    #pragma unroll
    for (int f = 0; f < 2; ++f) {
        const int ft = 2 * w + f;
        wb1[f] = get_frag<MODE>(wsb, P, mlp, ft, 0, 16 * ft + lr, 8 * lg, lane);
        b1v[f] = MODE ? ld4(bias + 16 * ft + 4 * lg) : ld4(P.b1 + 16 * ft + 4 * lg);
    }
    __builtin_amdgcn_sched_barrier(0);   // keep loads batched above the loop
    #pragma unroll
    for (int m = 0; m < 2; ++m) {
        const int r = 16 * m + lr;
        bf16x8 bh = *reinterpret_cast<const bf16x8*>(ph + pbase + m * 1280);
        bf16x8 bl = *reinterpret_cast<const bf16x8*>(pl + pbase + m * 1280);
        #pragma unroll
        for (int f = 0; f < 2; ++f) {
            f32x4 acc = b1v[f];
            acc = mfma16(wb1[f], bh, acc);
            acc = mfma16(wb1[f], bl, acc);
            u32x2 pp = { pk2bf(fmaxf(acc[0], 0.f), fmaxf(acc[1], 0.f)),
                         pk2bf(fmaxf(acc[2], 0.f), fmaxf(acc[3], 0.f)) };
            *reinterpret_cast<u32x2*>(h1 + r * 256 + (f ? wslot1 : wslot0)) = pp;
        }
    }
    __syncthreads();

    // ---------- layer 2: K=128 ----------
    bf16x8 wb2[2][4]; f32x4 b2v[2];
    #pragma unroll
    for (int f = 0; f < 2; ++f) {
        const int ft = 2 * w + f;
        #pragma unroll
        for (int ks = 0; ks < 4; ++ks)
            wb2[f][ks] = get_frag<MODE>(wsb, P, mlp, 8 + ft * 4 + ks, 1,
                                        16 * ft + lr, 32 * ks + 8 * lg, lane);
        b2v[f] = MODE ? ld4(bias + 128 + 16 * ft + 4 * lg) : ld4(P.b2 + 16 * ft + 4 * lg);
    }
    __builtin_amdgcn_sched_barrier(0);
    #pragma unroll
    for (int m = 0; m < 2; ++m) {
        const int r = 16 * m + lr;
        const char* rowp = h1 + r * 256;
        bf16x8 hf[4];
        #pragma unroll
        for (int ks = 0; ks < 4; ++ks)
            hf[ks] = *reinterpret_cast<const bf16x8*>(rowp + rslot[ks]);
        #pragma unroll
        for (int f = 0; f < 2; ++f) {
            f32x4 acc = b2v[f];
            #pragma unroll
            for (int ks = 0; ks < 4; ++ks)
                acc = mfma16(wb2[f][ks], hf[ks], acc);
            u32x2 pp = { pk2bf(fmaxf(acc[0], 0.f), fmaxf(acc[1], 0.f)),
                         pk2bf(fmaxf(acc[2], 0.f), fmaxf(acc[3], 0.f)) };
            *reinterpret_cast<u32x2*>(h2 + r * 256 + (f ? wslot1 : wslot0)) = pp;
        }
    }
    __syncthreads();

    // ---------- layer 3: K=128, interleaved s/t features ----------
    bf16x8 wb3[4];
    #pragma unroll
    for (int ks = 0; ks < 4; ++ks)
        wb3[ks] = get_frag<MODE>(wsb, P, mlp, 40 + 4 * w + ks, 2,
                                 feat3b(w, lr), 32 * ks + 8 * lg, lane);
    f32x4 b3v;
    if (MODE) {
        b3v = ld4(bias + 256 + 16 * w + 4 * lg);
    } else {
        float2 sa = *reinterpret_cast<const float2*>(P.b3 + 8 * w + 2 * lg);
        float2 sb = *reinterpret_cast<const float2*>(P.b3 + 32 + 8 * w + 2 * lg);
        b3v = f32x4{sa.x, sa.y, sb.x, sb.y};
    }
    if constexpr (PRE) {   // issue epilogue x-loads early; latency hides under L3
        #pragma unroll
        for (int m = 0; m < 2; ++m)
            xv[m] = *reinterpret_cast<const float2*>(gpre + (size_t)(16 * m + lr) * 64);
    }
    __builtin_amdgcn_sched_barrier(0);
    #pragma unroll
    for (int m = 0; m < 2; ++m) {
        const int r = 16 * m + lr;
        const char* rowp = h2 + r * 256;
        f32x4 acc = b3v;
        #pragma unroll
        for (int ks = 0; ks < 4; ++ks) {
            bf16x8 hg = *reinterpret_cast<const bf16x8*>(rowp + rslot[ks]);
            acc = mfma16(wb3[ks], hg, acc);
        }
        rr[m] = acc;
    }
}

// ---- weight prep: fragment tiles (1KB each) + biases (b3 permuted) ----
extern "C" __global__ void __launch_bounds__(256)
glow_prep(const float* __restrict__ s2w1, const float* __restrict__ s2w2,
          const float* __restrict__ s2w3, const float* __restrict__ s1w1,
          const float* __restrict__ s1w2, const float* __restrict__ s1w3,
          const float* __restrict__ s2b1, const float* __restrict__ s2b2,
          const float* __restrict__ s2b3, const float* __restrict__ s1b1,
          const float* __restrict__ s1b2, const float* __restrict__ s1b3,
          char* __restrict__ wsb)
{
    const int wave = threadIdx.x >> 6, lane = threadIdx.x & 63;
    const int lr = lane & 15, lg = lane >> 4;
    const int gw = blockIdx.x * 4 + wave;

    if (gw < 112) {
        int mlp = gw / 56, t = gw % 56;
        const float* Ws[2][3] = {{s2w1, s2w2, s2w3}, {s1w1, s1w2, s1w3}};
        const float* W; int K, row, k0;
        if (t < 8)       { W = Ws[mlp][0]; K = 32;  row = 16 * t + lr;          k0 = lg * 8; }
        else if (t < 40) { int u = t - 8;  W = Ws[mlp][1]; K = 128; row = 16 * (u >> 2) + lr; k0 = 32 * (u & 3) + lg * 8; }
        else             { int u = t - 40; W = Ws[mlp][2]; K = 128; row = feat3b(u >> 2, lr); k0 = 32 * (u & 3) + lg * 8; }
        const float* p = W + (size_t)row * K + k0;
        union U { uint4 q; bf16x8 v; } u;
        #pragma unroll
        for (int j = 0; j < 8; ++j) u.v[j] = (short)f2bf(p[j]);
        reinterpret_cast<uint4*>(wsb)[gw * 64 + lane] = u.q;
    } else if (blockIdx.x == 28) {
        const float* Bs[2][3] = {{s2b1, s2b2, s2b3}, {s1b1, s1b2, s1b3}};
        float* dst = reinterpret_cast<float*>(wsb + BIAS_OFF);
        for (int i = threadIdx.x; i < 640; i += 256) {
            int mlp = i / 320, j = i % 320;
            float v;
            if (j < 128)      v = Bs[mlp][0][j];
            else if (j < 256) v = Bs[mlp][1][j - 128];
            else { int k = j - 256; v = Bs[mlp][2][feat3b(k >> 4, k & 15)]; }
            dst[i] = v;
        }
    }
}

template<int MODE>
__global__ void __launch_bounds__(256, 8)
glow_main(const float* __restrict__ x,
          const float* __restrict__ s1w1, const float* __restrict__ s1b1,
          const float* __restrict__ s1w2, const float* __restrict__ s1b2,
          const float* __restrict__ s1w3, const float* __restrict__ s1b3,
          const float* __restrict__ s2w1, const float* __restrict__ s2b1,
          const float* __restrict__ s2w2, const float* __restrict__ s2b2,
          const float* __restrict__ s2w3, const float* __restrict__ s2b3,
          const char* __restrict__ wsb, float* __restrict__ out)
{
    __shared__ __align__(16) char lds[LDS_BYTES];
    char* A = lds;             // region A [32][256B]
    char* B = lds + 8192;      // region B [32][256B]
    // planes(x2) @ B[0:5120]; MLP0: L1 B->A, L2 A->B, L3 reads B
    // planes(y1) @ A[0:5120]; MLP1: L1 A->B, L2 B->A, L3 reads A

    const int tid  = threadIdx.x;
    const int w = tid >> 6, lane = tid & 63;
    const int lr = lane & 15, lg = lane >> 4;
    const size_t rowbase = (size_t)blockIdx.x * 32;
    const float* gx = x   + rowbase * 64;
    float*       go = out + rowbase * 64;

    const WPtrs P0 = {s2w1, s2b1, s2w2, s2b2, s2w3, s2b3};
    const WPtrs P1 = {s1w1, s1b1, s1w2, s1b2, s1w3, s1b3};

    const int c0 = 8 * w + 2 * lg;
    f32x4 rr[2];
    float2 xv[2];

    // ---- Phase A: pack x2 -> hi/lo planes @ B (32 rows x 32 cols, once) ----
    {
        int chunk = tid;                      // 256 chunks of 4 floats
        int r = chunk >> 3, c4 = (chunk & 7) * 4;
        f32x4 v = *reinterpret_cast<const f32x4*>(gx + (size_t)r * 64 + 32 + c4);
        unsigned int h0 = pk2bf(v[0], v[1]), h1p = pk2bf(v[2], v[3]);
        unsigned int l0 = pk2bf(v[0] - lo16f(h0),  v[1] - hi16f(h0));
        unsigned int l1 = pk2bf(v[2] - lo16f(h1p), v[3] - hi16f(h1p));
        *reinterpret_cast<u32x2*>(B + r * 80 + 2 * c4)        = u32x2{h0, h1p};
        *reinterpret_cast<u32x2*>(B + 2560 + r * 80 + 2 * c4) = u32x2{l0, l1};
    }
    __syncthreads();                                  // (1)

    // ---- MLP s2 on x2: L1 B->A, L2 A->B, L3 reads B (barriers 2,3) ----
    run_mlp<MODE, 1>(wsb, P0, 0, B, B + 2560, A, B, gx + c0, xv,
                     w, lg, lr, lane, rr);

    // ---- epilogue 1 (no barrier first: A dead since barrier 3) ----
    // y1 = e(s2)*x1 + t2 -> out cols 0..31 ; y1 planes -> A
    #pragma unroll
    for (int m = 0; m < 2; ++m) {
        const int r = 16 * m + lr;
        float y0 = fmaf(e_fun(rr[m][0]), xv[m].x, rr[m][2]);
        float y1 = fmaf(e_fun(rr[m][1]), xv[m].y, rr[m][3]);
        *reinterpret_cast<float2*>(go + (size_t)r * 64 + c0) = float2{y0, y1};
        unsigned int hh = pk2bf(y0, y1);
        unsigned int ll = pk2bf(y0 - lo16f(hh), y1 - hi16f(hh));
        *reinterpret_cast<unsigned int*>(A + r * 80 + 2 * c0)        = hh;
        *reinterpret_cast<unsigned int*>(A + 2560 + r * 80 + 2 * c0) = ll;
    }
    __syncthreads();                                  // (4)

    // ---- MLP s1 on y1: L1 A->B, L2 B->A, L3 reads A (barriers 5,6) ----
    run_mlp<MODE, 1>(wsb, P1, 1, A, A + 2560, B, A, gx + 32 + c0, xv,
                     w, lg, lr, lane, rr);

    // ---- epilogue 2: y2 = e(s1)*x2 + t1 -> out cols 32..63 (no LDS) ----
    #pragma unroll
    for (int m = 0; m < 2; ++m) {
        const int r = 16 * m + lr;
        float y0 = fmaf(e_fun(rr[m][0]), xv[m].x, rr[m][2]);
        float y1 = fmaf(e_fun(rr[m][1]), xv[m].y, rr[m][3]);
        *reinterpret_cast<float2*>(go + (size_t)r * 64 + 32 + c0) = float2{y0, y1};
    }
}

extern "C" void kernel_launch(void* const* d_in, const int* in_sizes, int n_in,
                              void* d_out, int out_size, void* d_ws, size_t ws_size,
                              hipStream_t stream) {
    const float* x    = (const float*)d_in[0];
    const float* s1w1 = (const float*)d_in[1];
    const float* s1b1 = (const float*)d_in[2];
    const float* s1w2 = (const float*)d_in[3];
    const float* s1b2 = (const float*)d_in[4];
    const float* s1w3 = (const float*)d_in[5];
    const float* s1b3 = (const float*)d_in[6];
    const float* s2w1 = (const float*)d_in[7];
    const float* s2b1 = (const float*)d_in[8];
    const float* s2w2 = (const float*)d_in[9];
    const float* s2b2 = (const float*)d_in[10];
    const float* s2w3 = (const float*)d_in[11];
    const float* s2b3 = (const float*)d_in[12];
    float* out = (float*)d_out;
    char* wsb  = (char*)d_ws;

    int nrows   = in_sizes[0] / 64;   // 262144
    int nblocks = nrows / 32;         // 8192

    if (ws_size >= (size_t)WS_NEED) {
        hipLaunchKernelGGL(glow_prep, dim3(29), dim3(256), 0, stream,
                           s2w1, s2w2, s2w3, s1w1, s1w2, s1w3,
                           s2b1, s2b2, s2b3, s1b1, s1b2, s1b3, wsb);
        hipLaunchKernelGGL((glow_main<1>), dim3(nblocks), dim3(256), 0, stream,
                           x, s1w1, s1b1, s1w2, s1b2, s1w3, s1b3,
                           s2w1, s2b1, s2w2, s2b2, s2w3, s2b3, wsb, out);
    } else {
        hipLaunchKernelGGL((glow_main<0>), dim3(nblocks), dim3(256), 0, stream,
                           x, s1w1, s1b1, s1w2, s1b2, s1w3, s1b3,
                           s2w1, s2b1, s2w2, s2b2, s2w3, s2b3, wsb, out);
    }
}

// Round 13
// 90.699 us; speedup vs baseline: 1.2201x; 1.2201x over previous
//
#include <hip/hip_runtime.h>
#include <hip/hip_bf16.h>

// Glow coupling layer, fused. rows N = 262144, C = 64.
// r2 = MLP_s2(x2); y1 = e(s2)*x1 + t2; r1 = MLP_s1(y1); y2 = e(s1)*x2 + t1.
//
// Round 13 = R10 structure with 48-ROW BLOCKS:
//   LDS 24KB (A/B regions 12KB) -> 6 blocks/CU (147456 <= 163840 w/ slack),
//   24 waves/CU. LB(256,6): VGPR cap 84 > 56 used -> no spill (R12's LB8
//   cap-64 spill disproved 8-wave; this is the feasible middle).
//   Grid 5462; tail block overlaps previous rows (identical values, benign).
//   All R10 pieces kept: region-swap 6-barrier plan, per-layer JIT weight
//   loads + sched_barrier(0), h [48][256B] XOR (r&7)<<4, planes [48][80B],
//   in-lane epilogue via W3 interleave, early epilogue x-loads.
//   Spill tripwire: WRITE_SIZE must stay ~65536 KB.
//
// MFMA v_mfma_f32_16x16x32_bf16, W = A-operand, activations = B-operand:
//   A frag: lane l holds A[row=l&15][k=(l>>4)*8+j]
//   B frag: lane l holds B[k=(l>>4)*8+j][col=l&15]
//   D     : lane l reg i -> (A-row = 4*(l>>4)+i, col = l&15)  [m89/m91]

using bf16x8 = __attribute__((ext_vector_type(8))) short;
using f32x4  = __attribute__((ext_vector_type(4))) float;
using u32x2  = __attribute__((ext_vector_type(2))) unsigned int;

__device__ __forceinline__ unsigned short f2bf(float f) {
    unsigned int u = __float_as_uint(f);
    u += 0x7FFFu + ((u >> 16) & 1u);
    return (unsigned short)(u >> 16);
}
__device__ __forceinline__ unsigned int pk2bf(float a, float b) {
    union { __hip_bfloat162 h; unsigned int u; } cv;
    cv.h = __float22bfloat162_rn(float2{a, b});
    return cv.u;   // low16 = bf16(a), high16 = bf16(b)
}
__device__ __forceinline__ float lo16f(unsigned int u) { return __uint_as_float(u << 16); }
__device__ __forceinline__ float hi16f(unsigned int u) { return __uint_as_float(u & 0xFFFF0000u); }

__device__ __forceinline__ f32x4 mfma16(bf16x8 a, bf16x8 b, f32x4 c) {
    return __builtin_amdgcn_mfma_f32_16x16x32_bf16(a, b, c, 0, 0, 0);
}

// e(s) = exp(3.18*atan(s/5)) = exp2(4.5877702*atan(0.2 s)); deg-11 minimax.
__device__ __forceinline__ float e_fun(float s) {
    float z = 0.2f * s;
    float a = fabsf(z);
    float t = fminf(a, __builtin_amdgcn_rcpf(a));   // a<=1 ? a : 1/a
    float u = t * t;
    float p = -0.0537741f;
    p = fmaf(p, u,  0.2415614f);
    p = fmaf(p, u, -0.5341673f);
    p = fmaf(p, u,  0.8879339f);
    p = fmaf(p, u, -1.5260000f);
    p = fmaf(p, u,  4.5876659f);
    p = p * t;
    float r = (a > 1.0f) ? (7.2064613f - p) : p;    // K*pi/2 - p
    r = copysignf(r, s);
    return __builtin_amdgcn_exp2f(r);
}

// W3 interleaved permutation: wave w, frag-row fr = 4q+i ->
//   i<2: s-feature 8w+2q+i ; i>=2: t-feature 32+8w+2q+(i-2)
__device__ __forceinline__ int feat3b(int w, int fr) {
    int q = fr >> 2, i = fr & 3;
    int base = 8 * w + 2 * q;
    return (i < 2) ? (base + i) : (32 + base + (i - 2));
}

// LDS: region A [48][256B] @0 (12288); region B [48][256B] @12288.
// planes (hi [48][80B]=3840 + lo [48][80B]) time-share region[0:7680].
#define LDS_BYTES 24576
#define ROWS 48

#define BIAS_OFF 114688           // 112 tiles * 1024B
#define WS_NEED  (114688 + 2560)

struct WPtrs { const float *w1, *b1, *w2, *b2, *w3, *b3; };

__device__ __forceinline__ bf16x8 load_wfrag(const float* __restrict__ W, int K, int frow, int k0) {
    const float4* p = reinterpret_cast<const float4*>(W + (size_t)frow * K + k0);
    float4 a = p[0], b = p[1];
    bf16x8 r;
    r[0] = (short)f2bf(a.x); r[1] = (short)f2bf(a.y);
    r[2] = (short)f2bf(a.z); r[3] = (short)f2bf(a.w);
    r[4] = (short)f2bf(b.x); r[5] = (short)f2bf(b.y);
    r[6] = (short)f2bf(b.z); r[7] = (short)f2bf(b.w);
    return r;
}

template<int MODE>
__device__ __forceinline__ bf16x8 get_frag(const char* wsb, const WPtrs& P, int mlp,
                                           int tile, int which, int row, int k0, int lane) {
    if constexpr (MODE != 0) {
        union { uint4 q; bf16x8 v; } u;
        u.q = reinterpret_cast<const uint4*>(wsb)[(mlp * 56 + tile) * 64 + lane];
        return u.v;
    } else {
        const float* W = (which == 0) ? P.w1 : (which == 1) ? P.w2 : P.w3;
        return load_wfrag(W, (which == 0) ? 32 : 128, row, k0);
    }
}

__device__ __forceinline__ f32x4 ld4(const float* p) {
    return *reinterpret_cast<const f32x4*>(p);
}

// ---- one 3-layer MLP over the 48-row tile, 4-wave f-split ----
// L1 input from planes ph/pl ([48][80B] hi/lo bf16).
// PRE=1: issue 3 float2 x-loads (gpre) before the L3 loop, return in xv.
// rr[m] regs: i<2 -> s at col 8w+2lg+i ; i>=2 -> t at col 8w+2lg+(i-2).
template<int MODE, int PRE>
__device__ __forceinline__ void run_mlp(
    const char* __restrict__ wsb, const WPtrs& P, int mlp,
    const char* __restrict__ ph, const char* __restrict__ pl,
    char* __restrict__ h1, char* __restrict__ h2,
    const float* __restrict__ gpre, float2 (&xv)[3],
    int w, int lg, int lr, int lane, f32x4 (&rr)[3])
{
    const int sw = (lr & 7) << 4;
    const float* bias = reinterpret_cast<const float*>(wsb + BIAS_OFF) + mlp * 320;

    // precomputed LDS slots (loop-invariant)
    int rslot[4];
    #pragma unroll
    for (int ks = 0; ks < 4; ++ks) rslot[ks] = (64 * ks + 16 * lg) ^ sw;
    const int wslot0 = (32 * (2 * w + 0) + 8 * lg) ^ sw;
    const int wslot1 = (32 * (2 * w + 1) + 8 * lg) ^ sw;
    const int pbase  = lr * 80 + 16 * lg;   // plane-read base (row lr)

    // ---------- layer 1: K=32 (hi+lo), wave's tiles ft = 2w, 2w+1 ----------
    bf16x8 wb1[2]; f32x4 b1v[2];
    #pragma unroll
    for (int f = 0; f < 2; ++f) {
        const int ft = 2 * w + f;
        wb1[f] = get_frag<MODE>(wsb, P, mlp, ft, 0, 16 * ft + lr, 8 * lg, lane);
        b1v[f] = MODE ? ld4(bias + 16 * ft + 4 * lg) : ld4(P.b1 + 16 * ft + 4 * lg);
    }
    __builtin_amdgcn_sched_barrier(0);   // keep loads batched above the loop
    #pragma unroll
    for (int m = 0; m < 3; ++m) {
        const int r = 16 * m + lr;
        bf16x8 bh = *reinterpret_cast<const bf16x8*>(ph + pbase + m * 1280);
        bf16x8 bl = *reinterpret_cast<const bf16x8*>(pl + pbase + m * 1280);
        #pragma unroll
        for (int f = 0; f < 2; ++f) {
            f32x4 acc = b1v[f];
            acc = mfma16(wb1[f], bh, acc);
            acc = mfma16(wb1[f], bl, acc);
            u32x2 pp = { pk2bf(fmaxf(acc[0], 0.f), fmaxf(acc[1], 0.f)),
                         pk2bf(fmaxf(acc[2], 0.f), fmaxf(acc[3], 0.f)) };
            *reinterpret_cast<u32x2*>(h1 + r * 256 + (f ? wslot1 : wslot0)) = pp;
        }
    }
    __syncthreads();

    // ---------- layer 2: K=128 ----------
    bf16x8 wb2[2][4]; f32x4 b2v[2];
    #pragma unroll
    for (int f = 0; f < 2; ++f) {
        const int ft = 2 * w + f;
        #pragma unroll
        for (int ks = 0; ks < 4; ++ks)
            wb2[f][ks] = get_frag<MODE>(wsb, P, mlp, 8 + ft * 4 + ks, 1,
                                        16 * ft + lr, 32 * ks + 8 * lg, lane);
        b2v[f] = MODE ? ld4(bias + 128 + 16 * ft + 4 * lg) : ld4(P.b2 + 16 * ft + 4 * lg);
    }
    __builtin_amdgcn_sched_barrier(0);
    #pragma unroll
    for (int m = 0; m < 3; ++m) {
        const int r = 16 * m + lr;
        const char* rowp = h1 + r * 256;
        bf16x8 hf[4];
        #pragma unroll
        for (int ks = 0; ks < 4; ++ks)
            hf[ks] = *reinterpret_cast<const bf16x8*>(rowp + rslot[ks]);
        #pragma unroll
        for (int f = 0; f < 2; ++f) {
            f32x4 acc = b2v[f];
            #pragma unroll
            for (int ks = 0; ks < 4; ++ks)
                acc = mfma16(wb2[f][ks], hf[ks], acc);
            u32x2 pp = { pk2bf(fmaxf(acc[0], 0.f), fmaxf(acc[1], 0.f)),
                         pk2bf(fmaxf(acc[2], 0.f), fmaxf(acc[3], 0.f)) };
            *reinterpret_cast<u32x2*>(h2 + r * 256 + (f ? wslot1 : wslot0)) = pp;
        }
    }
    __syncthreads();

    // ---------- layer 3: K=128, interleaved s/t features ----------
    bf16x8 wb3[4];
    #pragma unroll
    for (int ks = 0; ks < 4; ++ks)
        wb3[ks] = get_frag<MODE>(wsb, P, mlp, 40 + 4 * w + ks, 2,
                                 feat3b(w, lr), 32 * ks + 8 * lg, lane);
    f32x4 b3v;
    if (MODE) {
        b3v = ld4(bias + 256 + 16 * w + 4 * lg);
    } else {
        float2 sa = *reinterpret_cast<const float2*>(P.b3 + 8 * w + 2 * lg);
        float2 sb = *reinterpret_cast<const float2*>(P.b3 + 32 + 8 * w + 2 * lg);
        b3v = f32x4{sa.x, sa.y, sb.x, sb.y};
    }
    if constexpr (PRE) {   // issue epilogue x-loads early; latency hides under L3
        #pragma unroll
        for (int m = 0; m < 3; ++m)
            xv[m] = *reinterpret_cast<const float2*>(gpre + (size_t)(16 * m + lr) * 64);
    }
    __builtin_amdgcn_sched_barrier(0);
    #pragma unroll
    for (int m = 0; m < 3; ++m) {
        const int r = 16 * m + lr;
        const char* rowp = h2 + r * 256;
        f32x4 acc = b3v;
        #pragma unroll
        for (int ks = 0; ks < 4; ++ks) {
            bf16x8 hg = *reinterpret_cast<const bf16x8*>(rowp + rslot[ks]);
            acc = mfma16(wb3[ks], hg, acc);
        }
        rr[m] = acc;
    }
}

// ---- weight prep: fragment tiles (1KB each) + biases (b3 permuted) ----
extern "C" __global__ void __launch_bounds__(256)
glow_prep(const float* __restrict__ s2w1, const float* __restrict__ s2w2,
          const float* __restrict__ s2w3, const float* __restrict__ s1w1,
          const float* __restrict__ s1w2, const float* __restrict__ s1w3,
          const float* __restrict__ s2b1, const float* __restrict__ s2b2,
          const float* __restrict__ s2b3, const float* __restrict__ s1b1,
          const float* __restrict__ s1b2, const float* __restrict__ s1b3,
          char* __restrict__ wsb)
{
    const int wave = threadIdx.x >> 6, lane = threadIdx.x & 63;
    const int lr = lane & 15, lg = lane >> 4;
    const int gw = blockIdx.x * 4 + wave;

    if (gw < 112) {
        int mlp = gw / 56, t = gw % 56;
        const float* Ws[2][3] = {{s2w1, s2w2, s2w3}, {s1w1, s1w2, s1w3}};
        const float* W; int K, row, k0;
        if (t < 8)       { W = Ws[mlp][0]; K = 32;  row = 16 * t + lr;          k0 = lg * 8; }
        else if (t < 40) { int u = t - 8;  W = Ws[mlp][1]; K = 128; row = 16 * (u >> 2) + lr; k0 = 32 * (u & 3) + lg * 8; }
        else             { int u = t - 40; W = Ws[mlp][2]; K = 128; row = feat3b(u >> 2, lr); k0 = 32 * (u & 3) + lg * 8; }
        const float* p = W + (size_t)row * K + k0;
        union U { uint4 q; bf16x8 v; } u;
        #pragma unroll
        for (int j = 0; j < 8; ++j) u.v[j] = (short)f2bf(p[j]);
        reinterpret_cast<uint4*>(wsb)[gw * 64 + lane] = u.q;
    } else if (blockIdx.x == 28) {
        const float* Bs[2][3] = {{s2b1, s2b2, s2b3}, {s1b1, s1b2, s1b3}};
        float* dst = reinterpret_cast<float*>(wsb + BIAS_OFF);
        for (int i = threadIdx.x; i < 640; i += 256) {
            int mlp = i / 320, j = i % 320;
            float v;
            if (j < 128)      v = Bs[mlp][0][j];
            else if (j < 256) v = Bs[mlp][1][j - 128];
            else { int k = j - 256; v = Bs[mlp][2][feat3b(k >> 4, k & 15)]; }
            dst[i] = v;
        }
    }
}

template<int MODE>
__global__ void __launch_bounds__(256, 6)
glow_main(const float* __restrict__ x,
          const float* __restrict__ s1w1, const float* __restrict__ s1b1,
          const float* __restrict__ s1w2, const float* __restrict__ s1b2,
          const float* __restrict__ s1w3, const float* __restrict__ s1b3,
          const float* __restrict__ s2w1, const float* __restrict__ s2b1,
          const float* __restrict__ s2w2, const float* __restrict__ s2b2,
          const float* __restrict__ s2w3, const float* __restrict__ s2b3,
          const char* __restrict__ wsb, float* __restrict__ out, int nrows)
{
    __shared__ __align__(16) char lds[LDS_BYTES];
    char* A = lds;             // region A [48][256B]
    char* B = lds + 12288;     // region B [48][256B]
    // planes(x2) @ B[0:7680]; MLP0: L1 B->A, L2 A->B, L3 reads B
    // planes(y1) @ A[0:7680]; MLP1: L1 A->B, L2 B->A, L3 reads A

    const int tid  = threadIdx.x;
    const int w = tid >> 6, lane = tid & 63;
    const int lr = lane & 15, lg = lane >> 4;
    size_t rowbase = (size_t)blockIdx.x * ROWS;
    if (rowbase + ROWS > (size_t)nrows) rowbase = (size_t)nrows - ROWS;  // tail overlap, benign
    const float* gx = x   + rowbase * 64;
    float*       go = out + rowbase * 64;

    const WPtrs P0 = {s2w1, s2b1, s2w2, s2b2, s2w3, s2b3};
    const WPtrs P1 = {s1w1, s1b1, s1w2, s1b2, s1w3, s1b3};

    const int c0 = 8 * w + 2 * lg;
    f32x4 rr[3];
    float2 xv[3];

    // ---- Phase A: pack x2 -> hi/lo planes @ B (48 rows x 32 cols, once) ----
    #pragma unroll
    for (int it = 0; it < 2; ++it) {
        int chunk = it * 256 + tid;           // 384 chunks of 4 floats
        if (chunk < 384) {
            int r = chunk >> 3, c4 = (chunk & 7) * 4;
            f32x4 v = *reinterpret_cast<const f32x4*>(gx + (size_t)r * 64 + 32 + c4);
            unsigned int h0 = pk2bf(v[0], v[1]), h1p = pk2bf(v[2], v[3]);
            unsigned int l0 = pk2bf(v[0] - lo16f(h0),  v[1] - hi16f(h0));
            unsigned int l1 = pk2bf(v[2] - lo16f(h1p), v[3] - hi16f(h1p));
            *reinterpret_cast<u32x2*>(B + r * 80 + 2 * c4)        = u32x2{h0, h1p};
            *reinterpret_cast<u32x2*>(B + 3840 + r * 80 + 2 * c4) = u32x2{l0, l1};
        }
    }
    __syncthreads();                                  // (1)

    // ---- MLP s2 on x2: L1 B->A, L2 A->B, L3 reads B (barriers 2,3) ----
    run_mlp<MODE, 1>(wsb, P0, 0, B, B + 3840, A, B, gx + c0, xv,
                     w, lg, lr, lane, rr);

    // ---- epilogue 1 (no barrier first: A dead since barrier 3) ----
    // y1 = e(s2)*x1 + t2 -> out cols 0..31 ; y1 planes -> A
    #pragma unroll
    for (int m = 0; m < 3; ++m) {
        const int r = 16 * m + lr;
        float y0 = fmaf(e_fun(rr[m][0]), xv[m].x, rr[m][2]);
        float y1 = fmaf(e_fun(rr[m][1]), xv[m].y, rr[m][3]);
        *reinterpret_cast<float2*>(go + (size_t)r * 64 + c0) = float2{y0, y1};
        unsigned int hh = pk2bf(y0, y1);
        unsigned int ll = pk2bf(y0 - lo16f(hh), y1 - hi16f(hh));
        *reinterpret_cast<unsigned int*>(A + r * 80 + 2 * c0)        = hh;
        *reinterpret_cast<unsigned int*>(A + 3840 + r * 80 + 2 * c0) = ll;
    }
    __syncthreads();                                  // (4)

    // ---- MLP s1 on y1: L1 A->B, L2 B->A, L3 reads A (barriers 5,6) ----
    run_mlp<MODE, 1>(wsb, P1, 1, A, A + 3840, B, A, gx + 32 + c0, xv,
                     w, lg, lr, lane, rr);

    // ---- epilogue 2: y2 = e(s1)*x2 + t1 -> out cols 32..63 (no LDS) ----
    #pragma unroll
    for (int m = 0; m < 3; ++m) {
        const int r = 16 * m + lr;
        float y0 = fmaf(e_fun(rr[m][0]), xv[m].x, rr[m][2]);
        float y1 = fmaf(e_fun(rr[m][1]), xv[m].y, rr[m][3]);
        *reinterpret_cast<float2*>(go + (size_t)r * 64 + 32 + c0) = float2{y0, y1};
    }
}

extern "C" void kernel_launch(void* const* d_in, const int* in_sizes, int n_in,
                              void* d_out, int out_size, void* d_ws, size_t ws_size,
                              hipStream_t stream) {
    const float* x    = (const float*)d_in[0];
    const float* s1w1 = (const float*)d_in[1];
    const float* s1b1 = (const float*)d_in[2];
    const float* s1w2 = (const float*)d_in[3];
    const float* s1b2 = (const float*)d_in[4];
    const float* s1w3 = (const float*)d_in[5];
    const float* s1b3 = (const float*)d_in[6];
    const float* s2w1 = (const float*)d_in[7];
    const float* s2b1 = (const float*)d_in[8];
    const float* s2w2 = (const float*)d_in[9];
    const float* s2b2 = (const float*)d_in[10];
    const float* s2w3 = (const float*)d_in[11];
    const float* s2b3 = (const float*)d_in[12];
    float* out = (float*)d_out;
    char* wsb  = (char*)d_ws;

    int nrows   = in_sizes[0] / 64;            // 262144
    int nblocks = (nrows + ROWS - 1) / ROWS;   // 5462

    if (ws_size >= (size_t)WS_NEED) {
        hipLaunchKernelGGL(glow_prep, dim3(29), dim3(256), 0, stream,
                           s2w1, s2w2, s2w3, s1w1, s1w2, s1w3,
                           s2b1, s2b2, s2b3, s1b1, s1b2, s1b3, wsb);
        hipLaunchKernelGGL((glow_main<1>), dim3(nblocks), dim3(256), 0, stream,
                           x, s1w1, s1b1, s1w2, s1b2, s1w3, s1b3,
                           s2w1, s2b1, s2w2, s2b2, s2w3, s2b3, wsb, out, nrows);
    } else {
        hipLaunchKernelGGL((glow_main<0>), dim3(nblocks), dim3(256), 0, stream,
                           x, s1w1, s1b1, s1w2, s1b2, s1w3, s1b3,
                           s2w1, s2b1, s2w2, s2b2, s2w3, s2b3, wsb, out, nrows);
    }
}

// Round 14
// 75.934 us; speedup vs baseline: 1.4574x; 1.1944x over previous
//
#include <hip/hip_runtime.h>
#include <hip/hip_bf16.h>

// Glow coupling layer, fused. rows N = 262144, C = 64.
// r2 = MLP_s2(x2); y1 = e(s2)*x1 + t2; r1 = MLP_s1(y1); y2 = e(s1)*x2 + t1.
//
// Round 14 = R10 flow rebuilt on v_mfma_f32_32x32x16_bf16 (was 16x16x32):
//  - half the MFMA instructions, 15% higher MFMA rate, L3 LDS reads halved
//  - 64-row block, 4 waves; wave w: L1/L2 f-tile = w (32 feats);
//    L3 tile T3 = w&1 (16 s + 16 t feats, permuted), row-group rg3 = w>>1
//  - W3 perm: tile-local row p -> orig feat: p<16 ? 16T+p : 16+16T+p
//    => lane regs pair s (i<8) with matching t (i+8); bias loads stay plain
//  - L1 B-frags for MLP0 straight from global (no phase A; 5 barriers)
//  - h [64][256B] XOR (r&7)<<4; planes [64][80B] (y1 only) — all access
//    patterns re-derived bank-optimal for the 32-row fragment shapes
//  - LB(256,4) (proven no-spill region), LDS 32KB, region-swap A/B
//
// 32x32x16 layouts: C/D col=lane&31, row=(i&3)+8*(i>>2)+4*(lane>>5) [m74/m101]
//   A: lane holds A[row=lane&31][k=(lane>>5)*8+j]; B mirrors (col=lane&31).

using bf16x8 = __attribute__((ext_vector_type(8))) short;
using f32x4  = __attribute__((ext_vector_type(4))) float;
using f32x16 = __attribute__((ext_vector_type(16))) float;
using u32x2  = __attribute__((ext_vector_type(2))) unsigned int;

__device__ __forceinline__ unsigned short f2bf(float f) {
    unsigned int u = __float_as_uint(f);
    u += 0x7FFFu + ((u >> 16) & 1u);
    return (unsigned short)(u >> 16);
}
__device__ __forceinline__ unsigned int pk2bf(float a, float b) {
    union { __hip_bfloat162 h; unsigned int u; } cv;
    cv.h = __float22bfloat162_rn(float2{a, b});
    return cv.u;   // low16 = bf16(a), high16 = bf16(b)
}
__device__ __forceinline__ float lo16f(unsigned int u) { return __uint_as_float(u << 16); }
__device__ __forceinline__ float hi16f(unsigned int u) { return __uint_as_float(u & 0xFFFF0000u); }

__device__ __forceinline__ f32x16 mfma32(bf16x8 a, bf16x8 b, f32x16 c) {
    return __builtin_amdgcn_mfma_f32_32x32x16_bf16(a, b, c, 0, 0, 0);
}

// e(s) = exp(3.18*atan(s/5)) = exp2(4.5877702*atan(0.2 s)); deg-11 minimax.
__device__ __forceinline__ float e_fun(float s) {
    float z = 0.2f * s;
    float a = fabsf(z);
    float t = fminf(a, __builtin_amdgcn_rcpf(a));   // a<=1 ? a : 1/a
    float u = t * t;
    float p = -0.0537741f;
    p = fmaf(p, u,  0.2415614f);
    p = fmaf(p, u, -0.5341673f);
    p = fmaf(p, u,  0.8879339f);
    p = fmaf(p, u, -1.5260000f);
    p = fmaf(p, u,  4.5876659f);
    p = p * t;
    float r = (a > 1.0f) ? (7.2064613f - p) : p;    // K*pi/2 - p
    r = copysignf(r, s);
    return __builtin_amdgcn_exp2f(r);
}

// W3 row permutation (tile T, tile-local row p = jj + 8q + 4g):
__device__ __forceinline__ int perm3(int T, int p) {
    return p < 16 ? 16 * T + p : 16 + 16 * T + p;
}

// LDS: region A [64][256B] @0 (16384); region B [64][256B] @16384.
// y1 planes (hi [64][80B]=5120 + lo 5120) time-share a region's first 10240B.
#define LDS_BYTES 32768

#define BIAS_OFF 114688           // 112 tiles * 1024B
#define WS_NEED  (114688 + 2560)

struct WPtrs { const float *w1, *b1, *w2, *b2, *w3, *b3; };

__device__ __forceinline__ bf16x8 load_wfrag(const float* __restrict__ W, int K, int frow, int k0) {
    const float4* p = reinterpret_cast<const float4*>(W + (size_t)frow * K + k0);
    float4 a = p[0], b = p[1];
    bf16x8 r;
    r[0] = (short)f2bf(a.x); r[1] = (short)f2bf(a.y);
    r[2] = (short)f2bf(a.z); r[3] = (short)f2bf(a.w);
    r[4] = (short)f2bf(b.x); r[5] = (short)f2bf(b.y);
    r[6] = (short)f2bf(b.z); r[7] = (short)f2bf(b.w);
    return r;
}

template<int MODE>
__device__ __forceinline__ bf16x8 get_frag(const char* wsb, const WPtrs& P, int mlp,
                                           int tile, int which, int row, int k0, int lane) {
    if constexpr (MODE != 0) {
        union { uint4 q; bf16x8 v; } u;
        u.q = reinterpret_cast<const uint4*>(wsb)[(mlp * 56 + tile) * 64 + lane];
        return u.v;
    } else {
        const float* W = (which == 0) ? P.w1 : (which == 1) ? P.w2 : P.w3;
        return load_wfrag(W, (which == 0) ? 32 : 128, row, k0);
    }
}

__device__ __forceinline__ f32x4 ld4(const float* p) {
    return *reinterpret_cast<const f32x4*>(p);
}

// ---- one 3-layer MLP over the 64-row tile, 32x32 MFMA ----
// SRC=0: L1 B-frags from global x2 (gx). SRC=1: from planes ph/pl.
// acc3 = L3 result for this wave's (T3, rg3): reg i: p=(i&3)+8*(i>>2)+4g;
//   i<8 -> s-feat 16T3+p ; i>=8 -> t-feat 32+16T3+(p-16), paired with i-8.
template<int MODE, int SRC>
__device__ __forceinline__ void run_mlp(
    const char* __restrict__ wsb, const WPtrs& P, int mlp,
    const float* __restrict__ gx,
    const char* __restrict__ ph, const char* __restrict__ pl,
    char* __restrict__ h1, char* __restrict__ h2,
    const float* __restrict__ gpre, f32x4 (&xv)[2],
    int w, int g, int col, int lane, int T3, int rg3, f32x16& acc3)
{
    const int sw = (col & 7) << 4;
    const float* bias = reinterpret_cast<const float*>(wsb + BIAS_OFF) + mlp * 320;
    const int ft = w;

    // ---------- layer 1: K=32 (2 ksteps, hi+lo) ----------
    bf16x8 wb1[2];
    #pragma unroll
    for (int ks = 0; ks < 2; ++ks)
        wb1[ks] = get_frag<MODE>(wsb, P, mlp, 2 * ft + ks, 0, 32 * ft + col, 16 * ks + 8 * g, lane);
    f32x4 bq[4];
    #pragma unroll
    for (int q = 0; q < 4; ++q)
        bq[q] = MODE ? ld4(bias + 32 * ft + 8 * q + 4 * g) : ld4(P.b1 + 32 * ft + 8 * q + 4 * g);
    __builtin_amdgcn_sched_barrier(0);
    #pragma unroll
    for (int rg = 0; rg < 2; ++rg) {
        const int r = 32 * rg + col;
        bf16x8 bh[2], bl[2];
        if constexpr (SRC == 0) {
            #pragma unroll
            for (int ks = 0; ks < 2; ++ks) {
                const float* xp = gx + (size_t)r * 64 + 32 + 16 * ks + 8 * g;
                f32x4 xa = ld4(xp), xb = ld4(xp + 4);
                union FB { bf16x8 v; unsigned int u[4]; } H, L;
                H.u[0] = pk2bf(xa[0], xa[1]); H.u[1] = pk2bf(xa[2], xa[3]);
                H.u[2] = pk2bf(xb[0], xb[1]); H.u[3] = pk2bf(xb[2], xb[3]);
                L.u[0] = pk2bf(xa[0] - lo16f(H.u[0]), xa[1] - hi16f(H.u[0]));
                L.u[1] = pk2bf(xa[2] - lo16f(H.u[1]), xa[3] - hi16f(H.u[1]));
                L.u[2] = pk2bf(xb[0] - lo16f(H.u[2]), xb[1] - hi16f(H.u[2]));
                L.u[3] = pk2bf(xb[2] - lo16f(H.u[3]), xb[3] - hi16f(H.u[3]));
                bh[ks] = H.v; bl[ks] = L.v;
            }
        } else {
            #pragma unroll
            for (int ks = 0; ks < 2; ++ks) {
                bh[ks] = *reinterpret_cast<const bf16x8*>(ph + r * 80 + 16 * g + 32 * ks);
                bl[ks] = *reinterpret_cast<const bf16x8*>(pl + r * 80 + 16 * g + 32 * ks);
            }
        }
        f32x16 acc;
        #pragma unroll
        for (int q = 0; q < 4; ++q) {
            acc[4*q+0] = bq[q][0]; acc[4*q+1] = bq[q][1];
            acc[4*q+2] = bq[q][2]; acc[4*q+3] = bq[q][3];
        }
        #pragma unroll
        for (int ks = 0; ks < 2; ++ks) {
            acc = mfma32(wb1[ks], bh[ks], acc);
            acc = mfma32(wb1[ks], bl[ks], acc);
        }
        char* wp = h1 + r * 256;
        #pragma unroll
        for (int q = 0; q < 4; ++q) {
            u32x2 pp = { pk2bf(fmaxf(acc[4*q+0], 0.f), fmaxf(acc[4*q+1], 0.f)),
                         pk2bf(fmaxf(acc[4*q+2], 0.f), fmaxf(acc[4*q+3], 0.f)) };
            *reinterpret_cast<u32x2*>(wp + ((64 * ft + 16 * q + 8 * g) ^ sw)) = pp;
        }
    }
    __syncthreads();

    // ---------- layer 2: K=128 (8 ksteps) ----------
    bf16x8 wb2[8];
    #pragma unroll
    for (int ks = 0; ks < 8; ++ks)
        wb2[ks] = get_frag<MODE>(wsb, P, mlp, 8 + ft * 8 + ks, 1, 32 * ft + col, 16 * ks + 8 * g, lane);
    #pragma unroll
    for (int q = 0; q < 4; ++q)
        bq[q] = MODE ? ld4(bias + 128 + 32 * ft + 8 * q + 4 * g) : ld4(P.b2 + 32 * ft + 8 * q + 4 * g);
    __builtin_amdgcn_sched_barrier(0);
    #pragma unroll
    for (int rg = 0; rg < 2; ++rg) {
        const int r = 32 * rg + col;
        const char* rp = h1 + r * 256;
        f32x16 acc;
        #pragma unroll
        for (int q = 0; q < 4; ++q) {
            acc[4*q+0] = bq[q][0]; acc[4*q+1] = bq[q][1];
            acc[4*q+2] = bq[q][2]; acc[4*q+3] = bq[q][3];
        }
        #pragma unroll
        for (int ks = 0; ks < 8; ++ks) {
            bf16x8 hf = *reinterpret_cast<const bf16x8*>(rp + ((16 * g + 32 * ks) ^ sw));
            acc = mfma32(wb2[ks], hf, acc);
        }
        char* wp = h2 + r * 256;
        #pragma unroll
        for (int q = 0; q < 4; ++q) {
            u32x2 pp = { pk2bf(fmaxf(acc[4*q+0], 0.f), fmaxf(acc[4*q+1], 0.f)),
                         pk2bf(fmaxf(acc[4*q+2], 0.f), fmaxf(acc[4*q+3], 0.f)) };
            *reinterpret_cast<u32x2*>(wp + ((64 * ft + 16 * q + 8 * g) ^ sw)) = pp;
        }
    }
    __syncthreads();

    // ---------- layer 3: K=128, this wave's (T3, rg3) only ----------
    bf16x8 wb3[8];
    #pragma unroll
    for (int ks = 0; ks < 8; ++ks)
        wb3[ks] = get_frag<MODE>(wsb, P, mlp, 40 + T3 * 8 + ks, 2, perm3(T3, col), 16 * ks + 8 * g, lane);
    f32x4 b3q[4];
    #pragma unroll
    for (int q = 0; q < 4; ++q) {
        const int base = (q < 2) ? (16 * T3 + 8 * q + 4 * g)
                                 : (32 + 16 * T3 + 8 * (q - 2) + 4 * g);
        b3q[q] = MODE ? ld4(bias + 256 + base) : ld4(P.b3 + base);
    }
    const int r3 = 32 * rg3 + col;
    #pragma unroll
    for (int Q = 0; Q < 2; ++Q)   // early epilogue x loads; hide under L3 MFMA
        xv[Q] = ld4(gpre + (size_t)r3 * 64 + 16 * T3 + 8 * Q + 4 * g);
    __builtin_amdgcn_sched_barrier(0);
    {
        const char* rp = h2 + r3 * 256;
        f32x16 acc;
        #pragma unroll
        for (int q = 0; q < 4; ++q) {
            acc[4*q+0] = b3q[q][0]; acc[4*q+1] = b3q[q][1];
            acc[4*q+2] = b3q[q][2]; acc[4*q+3] = b3q[q][3];
        }
        #pragma unroll
        for (int ks = 0; ks < 8; ++ks) {
            bf16x8 hg = *reinterpret_cast<const bf16x8*>(rp + ((16 * g + 32 * ks) ^ sw));
            acc = mfma32(wb3[ks], hg, acc);
        }
        acc3 = acc;
    }
}

// ---- weight prep: 112 fragment tiles (1KB each, 32x32 layout) + plain biases ----
extern "C" __global__ void __launch_bounds__(256)
glow_prep(const float* __restrict__ s2w1, const float* __restrict__ s2w2,
          const float* __restrict__ s2w3, const float* __restrict__ s1w1,
          const float* __restrict__ s1w2, const float* __restrict__ s1w3,
          const float* __restrict__ s2b1, const float* __restrict__ s2b2,
          const float* __restrict__ s2b3, const float* __restrict__ s1b1,
          const float* __restrict__ s1b2, const float* __restrict__ s1b3,
          char* __restrict__ wsb)
{
    const int wave = threadIdx.x >> 6, lane = threadIdx.x & 63;
    const int col = lane & 31, g = lane >> 5;
    const int gw = blockIdx.x * 4 + wave;

    if (gw < 112) {
        int mlp = gw / 56, t = gw % 56;
        const float* Ws[2][3] = {{s2w1, s2w2, s2w3}, {s1w1, s1w2, s1w3}};
        const float* W; int K, row, k0;
        if (t < 8)       { W = Ws[mlp][0]; K = 32;  int ft = t >> 1, ks = t & 1;
                           row = 32 * ft + col; k0 = 16 * ks + 8 * g; }
        else if (t < 40) { int u = t - 8;  W = Ws[mlp][1]; K = 128; int ft = u >> 3, ks = u & 7;
                           row = 32 * ft + col; k0 = 16 * ks + 8 * g; }
        else             { int u = t - 40; W = Ws[mlp][2]; K = 128; int T = u >> 3, ks = u & 7;
                           row = perm3(T, col); k0 = 16 * ks + 8 * g; }
        const float* p = W + (size_t)row * K + k0;
        union U { uint4 q; bf16x8 v; } u;
        #pragma unroll
        for (int j = 0; j < 8; ++j) u.v[j] = (short)f2bf(p[j]);
        reinterpret_cast<uint4*>(wsb)[gw * 64 + lane] = u.q;
    } else if (blockIdx.x == 28) {
        const float* Bs[2][3] = {{s2b1, s2b2, s2b3}, {s1b1, s1b2, s1b3}};
        float* dst = reinterpret_cast<float*>(wsb + BIAS_OFF);
        for (int i = threadIdx.x; i < 640; i += 256) {
            int mlp = i / 320, j = i % 320;
            float v;
            if (j < 128)      v = Bs[mlp][0][j];
            else if (j < 256) v = Bs[mlp][1][j - 128];
            else              v = Bs[mlp][2][j - 256];
            dst[i] = v;
        }
    }
}

template<int MODE>
__global__ void __launch_bounds__(256, 4)
glow_main(const float* __restrict__ x,
          const float* __restrict__ s1w1, const float* __restrict__ s1b1,
          const float* __restrict__ s1w2, const float* __restrict__ s1b2,
          const float* __restrict__ s1w3, const float* __restrict__ s1b3,
          const float* __restrict__ s2w1, const float* __restrict__ s2b1,
          const float* __restrict__ s2w2, const float* __restrict__ s2b2,
          const float* __restrict__ s2w3, const float* __restrict__ s2b3,
          const char* __restrict__ wsb, float* __restrict__ out)
{
    __shared__ __align__(16) char lds[LDS_BYTES];
    char* A = lds;             // region A [64][256B]
    char* B = lds + 16384;     // region B [64][256B]
    // MLP0: L1(global)->A, L2 A->B, L3 reads B; epi1 planes -> A[0:10240]
    // MLP1: L1(planes A)->B, L2 B->A, L3 reads A

    const int tid  = threadIdx.x;
    const int w = tid >> 6, lane = tid & 63;
    const int col = lane & 31, g = lane >> 5;
    const int T3 = w & 1, rg3 = w >> 1;
    const size_t rowbase = (size_t)blockIdx.x * 64;
    const float* gx = x   + rowbase * 64;
    float*       go = out + rowbase * 64;

    const WPtrs P0 = {s2w1, s2b1, s2w2, s2b2, s2w3, s2b3};
    const WPtrs P1 = {s1w1, s1b1, s1w2, s1b2, s1w3, s1b3};

    f32x16 acc;
    f32x4 xv[2];
    const int r3 = 32 * rg3 + col;

    // ---- MLP s2 on x2 (L1 from global; barriers 1,2) ----
    run_mlp<MODE, 0>(wsb, P0, 0, gx, nullptr, nullptr, A, B, gx, xv,
                     w, g, col, lane, T3, rg3, acc);

    // ---- epilogue 1: y1 = e(s2)*x1 + t2 -> out cols 0..31 + planes @ A ----
    #pragma unroll
    for (int Q = 0; Q < 2; ++Q) {
        const int scol = 16 * T3 + 8 * Q + 4 * g;
        f32x4 y;
        #pragma unroll
        for (int jj = 0; jj < 4; ++jj)
            y[jj] = fmaf(e_fun(acc[4 * Q + jj]), xv[Q][jj], acc[8 + 4 * Q + jj]);
        *reinterpret_cast<f32x4*>(go + (size_t)r3 * 64 + scol) = y;
        unsigned int h0 = pk2bf(y[0], y[1]), h1p = pk2bf(y[2], y[3]);
        unsigned int l0 = pk2bf(y[0] - lo16f(h0),  y[1] - hi16f(h0));
        unsigned int l1 = pk2bf(y[2] - lo16f(h1p), y[3] - hi16f(h1p));
        const int po = r3 * 80 + 32 * T3 + 16 * Q + 8 * g;
        *reinterpret_cast<u32x2*>(A + po)        = u32x2{h0, h1p};
        *reinterpret_cast<u32x2*>(A + 5120 + po) = u32x2{l0, l1};
    }
    __syncthreads();                                  // (3)

    // ---- MLP s1 on y1 (L1 from planes @ A; barriers 4,5) ----
    run_mlp<MODE, 1>(wsb, P1, 1, gx, A, A + 5120, B, A, gx + 32, xv,
                     w, g, col, lane, T3, rg3, acc);

    // ---- epilogue 2: y2 = e(s1)*x2 + t1 -> out cols 32..63 ----
    #pragma unroll
    for (int Q = 0; Q < 2; ++Q) {
        const int scol = 16 * T3 + 8 * Q + 4 * g;
        f32x4 y;
        #pragma unroll
        for (int jj = 0; jj < 4; ++jj)
            y[jj] = fmaf(e_fun(acc[4 * Q + jj]), xv[Q][jj], acc[8 + 4 * Q + jj]);
        *reinterpret_cast<f32x4*>(go + (size_t)r3 * 64 + 32 + scol) = y;
    }
}

extern "C" void kernel_launch(void* const* d_in, const int* in_sizes, int n_in,
                              void* d_out, int out_size, void* d_ws, size_t ws_size,
                              hipStream_t stream) {
    const float* x    = (const float*)d_in[0];
    const float* s1w1 = (const float*)d_in[1];
    const float* s1b1 = (const float*)d_in[2];
    const float* s1w2 = (const float*)d_in[3];
    const float* s1b2 = (const float*)d_in[4];
    const float* s1w3 = (const float*)d_in[5];
    const float* s1b3 = (const float*)d_in[6];
    const float* s2w1 = (const float*)d_in[7];
    const float* s2b1 = (const float*)d_in[8];
    const float* s2w2 = (const float*)d_in[9];
    const float* s2b2 = (const float*)d_in[10];
    const float* s2w3 = (const float*)d_in[11];
    const float* s2b3 = (const float*)d_in[12];
    float* out = (float*)d_out;
    char* wsb  = (char*)d_ws;

    int nrows   = in_sizes[0] / 64;   // 262144
    int nblocks = nrows / 64;         // 4096

    if (ws_size >= (size_t)WS_NEED) {
        hipLaunchKernelGGL(glow_prep, dim3(29), dim3(256), 0, stream,
                           s2w1, s2w2, s2w3, s1w1, s1w2, s1w3,
                           s2b1, s2b2, s2b3, s1b1, s1b2, s1b3, wsb);
        hipLaunchKernelGGL((glow_main<1>), dim3(nblocks), dim3(256), 0, stream,
                           x, s1w1, s1b1, s1w2, s1b2, s1w3, s1b3,
                           s2w1, s2b1, s2w2, s2b2, s2w3, s2b3, wsb, out);
    } else {
        hipLaunchKernelGGL((glow_main<0>), dim3(nblocks), dim3(256), 0, stream,
                           x, s1w1, s1b1, s1w2, s1b2, s1w3, s1b3,
                           s2w1, s2b1, s2w2, s2b2, s2w3, s2b3, wsb, out);
    }
}

// Round 15
// 71.483 us; speedup vs baseline: 1.5481x; 1.0623x over previous
//
#include <hip/hip_runtime.h>
#include <hip/hip_bf16.h>

// Glow coupling layer, fused. rows N = 262144, C = 64.
// r2 = MLP_s2(x2); y1 = e(s2)*x1 + t2; r1 = MLP_s1(y1); y2 = e(s1)*x2 + t1.
//
// Round 15 = R14 (32x32 MFMA) + once-only phase-A pack (R14's regression was
// every wave re-packing the SAME x2 B-frags from global, 4x duplicated VALU
// + exposed latency; B-operands are shared across f-tiles).
// Region plan (6 barriers): planes(x2)@B; MLP0 {L1 B->A, L2 A->B, L3 reads
// B}; epi1 planes(y1)@A (A dead since bar3); bar; MLP1 {L1 A->B, L2 B->A,
// L3 reads A}; epi2 (no LDS).
// Kept from R14: v_mfma_f32_32x32x16_bf16, W3 perm p<16?16T+p:16+16T+p
// (in-lane s/t pairing, plain bias loads), h [64][256B] XOR (r&7)<<4,
// planes [64][80B], per-layer JIT weight loads + sched_barrier(0),
// early epilogue x-loads, LB(256,4), LDS 32KB.
//
// 32x32x16 layouts: C/D col=lane&31, row=(i&3)+8*(i>>2)+4*(lane>>5) [m74/m101]
//   A: lane holds A[row=lane&31][k=(lane>>5)*8+j]; B mirrors (col=lane&31).

using bf16x8 = __attribute__((ext_vector_type(8))) short;
using f32x4  = __attribute__((ext_vector_type(4))) float;
using f32x16 = __attribute__((ext_vector_type(16))) float;
using u32x2  = __attribute__((ext_vector_type(2))) unsigned int;

__device__ __forceinline__ unsigned short f2bf(float f) {
    unsigned int u = __float_as_uint(f);
    u += 0x7FFFu + ((u >> 16) & 1u);
    return (unsigned short)(u >> 16);
}
__device__ __forceinline__ unsigned int pk2bf(float a, float b) {
    union { __hip_bfloat162 h; unsigned int u; } cv;
    cv.h = __float22bfloat162_rn(float2{a, b});
    return cv.u;   // low16 = bf16(a), high16 = bf16(b)
}
__device__ __forceinline__ float lo16f(unsigned int u) { return __uint_as_float(u << 16); }
__device__ __forceinline__ float hi16f(unsigned int u) { return __uint_as_float(u & 0xFFFF0000u); }

__device__ __forceinline__ f32x16 mfma32(bf16x8 a, bf16x8 b, f32x16 c) {
    return __builtin_amdgcn_mfma_f32_32x32x16_bf16(a, b, c, 0, 0, 0);
}

// e(s) = exp(3.18*atan(s/5)) = exp2(4.5877702*atan(0.2 s)); deg-11 minimax.
__device__ __forceinline__ float e_fun(float s) {
    float z = 0.2f * s;
    float a = fabsf(z);
    float t = fminf(a, __builtin_amdgcn_rcpf(a));   // a<=1 ? a : 1/a
    float u = t * t;
    float p = -0.0537741f;
    p = fmaf(p, u,  0.2415614f);
    p = fmaf(p, u, -0.5341673f);
    p = fmaf(p, u,  0.8879339f);
    p = fmaf(p, u, -1.5260000f);
    p = fmaf(p, u,  4.5876659f);
    p = p * t;
    float r = (a > 1.0f) ? (7.2064613f - p) : p;    // K*pi/2 - p
    r = copysignf(r, s);
    return __builtin_amdgcn_exp2f(r);
}

// W3 row permutation (tile T, tile-local row p):
__device__ __forceinline__ int perm3(int T, int p) {
    return p < 16 ? 16 * T + p : 16 + 16 * T + p;
}

// LDS: region A [64][256B] @0 (16384); region B [64][256B] @16384.
// planes (hi [64][80B]=5120 + lo 5120) time-share a region's first 10240B.
#define LDS_BYTES 32768

#define BIAS_OFF 114688           // 112 tiles * 1024B
#define WS_NEED  (114688 + 2560)

struct WPtrs { const float *w1, *b1, *w2, *b2, *w3, *b3; };

__device__ __forceinline__ bf16x8 load_wfrag(const float* __restrict__ W, int K, int frow, int k0) {
    const float4* p = reinterpret_cast<const float4*>(W + (size_t)frow * K + k0);
    float4 a = p[0], b = p[1];
    bf16x8 r;
    r[0] = (short)f2bf(a.x); r[1] = (short)f2bf(a.y);
    r[2] = (short)f2bf(a.z); r[3] = (short)f2bf(a.w);
    r[4] = (short)f2bf(b.x); r[5] = (short)f2bf(b.y);
    r[6] = (short)f2bf(b.z); r[7] = (short)f2bf(b.w);
    return r;
}

template<int MODE>
__device__ __forceinline__ bf16x8 get_frag(const char* wsb, const WPtrs& P, int mlp,
                                           int tile, int which, int row, int k0, int lane) {
    if constexpr (MODE != 0) {
        union { uint4 q; bf16x8 v; } u;
        u.q = reinterpret_cast<const uint4*>(wsb)[(mlp * 56 + tile) * 64 + lane];
        return u.v;
    } else {
        const float* W = (which == 0) ? P.w1 : (which == 1) ? P.w2 : P.w3;
        return load_wfrag(W, (which == 0) ? 32 : 128, row, k0);
    }
}

__device__ __forceinline__ f32x4 ld4(const float* p) {
    return *reinterpret_cast<const f32x4*>(p);
}

// ---- one 3-layer MLP over the 64-row tile, 32x32 MFMA ----
// L1 B-frags from planes ph/pl ([64][80B] hi/lo bf16).
// acc3 = L3 result for this wave's (T3, rg3): reg i: p=(i&3)+8*(i>>2)+4g;
//   i<8 -> s-feat 16T3+p ; i>=8 -> t-feat 32+16T3+(p-16), paired with i-8.
template<int MODE>
__device__ __forceinline__ void run_mlp(
    const char* __restrict__ wsb, const WPtrs& P, int mlp,
    const char* __restrict__ ph, const char* __restrict__ pl,
    char* __restrict__ h1, char* __restrict__ h2,
    const float* __restrict__ gpre, f32x4 (&xv)[2],
    int w, int g, int col, int lane, int T3, int rg3, f32x16& acc3)
{
    const int sw = (col & 7) << 4;
    const float* bias = reinterpret_cast<const float*>(wsb + BIAS_OFF) + mlp * 320;
    const int ft = w;

    // ---------- layer 1: K=32 (2 ksteps, hi+lo planes) ----------
    bf16x8 wb1[2];
    #pragma unroll
    for (int ks = 0; ks < 2; ++ks)
        wb1[ks] = get_frag<MODE>(wsb, P, mlp, 2 * ft + ks, 0, 32 * ft + col, 16 * ks + 8 * g, lane);
    f32x4 bq[4];
    #pragma unroll
    for (int q = 0; q < 4; ++q)
        bq[q] = MODE ? ld4(bias + 32 * ft + 8 * q + 4 * g) : ld4(P.b1 + 32 * ft + 8 * q + 4 * g);
    __builtin_amdgcn_sched_barrier(0);
    #pragma unroll
    for (int rg = 0; rg < 2; ++rg) {
        const int r = 32 * rg + col;
        f32x16 acc;
        #pragma unroll
        for (int q = 0; q < 4; ++q) {
            acc[4*q+0] = bq[q][0]; acc[4*q+1] = bq[q][1];
            acc[4*q+2] = bq[q][2]; acc[4*q+3] = bq[q][3];
        }
        #pragma unroll
        for (int ks = 0; ks < 2; ++ks) {
            bf16x8 bh = *reinterpret_cast<const bf16x8*>(ph + r * 80 + 32 * ks + 16 * g);
            bf16x8 bl = *reinterpret_cast<const bf16x8*>(pl + r * 80 + 32 * ks + 16 * g);
            acc = mfma32(wb1[ks], bh, acc);
            acc = mfma32(wb1[ks], bl, acc);
        }
        char* wp = h1 + r * 256;
        #pragma unroll
        for (int q = 0; q < 4; ++q) {
            u32x2 pp = { pk2bf(fmaxf(acc[4*q+0], 0.f), fmaxf(acc[4*q+1], 0.f)),
                         pk2bf(fmaxf(acc[4*q+2], 0.f), fmaxf(acc[4*q+3], 0.f)) };
            *reinterpret_cast<u32x2*>(wp + ((64 * ft + 16 * q + 8 * g) ^ sw)) = pp;
        }
    }
    __syncthreads();

    // ---------- layer 2: K=128 (8 ksteps) ----------
    bf16x8 wb2[8];
    #pragma unroll
    for (int ks = 0; ks < 8; ++ks)
        wb2[ks] = get_frag<MODE>(wsb, P, mlp, 8 + ft * 8 + ks, 1, 32 * ft + col, 16 * ks + 8 * g, lane);
    #pragma unroll
    for (int q = 0; q < 4; ++q)
        bq[q] = MODE ? ld4(bias + 128 + 32 * ft + 8 * q + 4 * g) : ld4(P.b2 + 32 * ft + 8 * q + 4 * g);
    __builtin_amdgcn_sched_barrier(0);
    #pragma unroll
    for (int rg = 0; rg < 2; ++rg) {
        const int r = 32 * rg + col;
        const char* rp = h1 + r * 256;
        f32x16 acc;
        #pragma unroll
        for (int q = 0; q < 4; ++q) {
            acc[4*q+0] = bq[q][0]; acc[4*q+1] = bq[q][1];
            acc[4*q+2] = bq[q][2]; acc[4*q+3] = bq[q][3];
        }
        #pragma unroll
        for (int ks = 0; ks < 8; ++ks) {
            bf16x8 hf = *reinterpret_cast<const bf16x8*>(rp + ((16 * g + 32 * ks) ^ sw));
            acc = mfma32(wb2[ks], hf, acc);
        }
        char* wp = h2 + r * 256;
        #pragma unroll
        for (int q = 0; q < 4; ++q) {
            u32x2 pp = { pk2bf(fmaxf(acc[4*q+0], 0.f), fmaxf(acc[4*q+1], 0.f)),
                         pk2bf(fmaxf(acc[4*q+2], 0.f), fmaxf(acc[4*q+3], 0.f)) };
            *reinterpret_cast<u32x2*>(wp + ((64 * ft + 16 * q + 8 * g) ^ sw)) = pp;
        }
    }
    __syncthreads();

    // ---------- layer 3: K=128, this wave's (T3, rg3) only ----------
    bf16x8 wb3[8];
    #pragma unroll
    for (int ks = 0; ks < 8; ++ks)
        wb3[ks] = get_frag<MODE>(wsb, P, mlp, 40 + T3 * 8 + ks, 2, perm3(T3, col), 16 * ks + 8 * g, lane);
    f32x4 b3q[4];
    #pragma unroll
    for (int q = 0; q < 4; ++q) {
        const int base = (q < 2) ? (16 * T3 + 8 * q + 4 * g)
                                 : (32 + 16 * T3 + 8 * (q - 2) + 4 * g);
        b3q[q] = MODE ? ld4(bias + 256 + base) : ld4(P.b3 + base);
    }
    const int r3 = 32 * rg3 + col;
    #pragma unroll
    for (int Q = 0; Q < 2; ++Q)   // early epilogue x loads; hide under L3 MFMA
        xv[Q] = ld4(gpre + (size_t)r3 * 64 + 16 * T3 + 8 * Q + 4 * g);
    __builtin_amdgcn_sched_barrier(0);
    {
        const char* rp = h2 + r3 * 256;
        f32x16 acc;
        #pragma unroll
        for (int q = 0; q < 4; ++q) {
            acc[4*q+0] = b3q[q][0]; acc[4*q+1] = b3q[q][1];
            acc[4*q+2] = b3q[q][2]; acc[4*q+3] = b3q[q][3];
        }
        #pragma unroll
        for (int ks = 0; ks < 8; ++ks) {
            bf16x8 hg = *reinterpret_cast<const bf16x8*>(rp + ((16 * g + 32 * ks) ^ sw));
            acc = mfma32(wb3[ks], hg, acc);
        }
        acc3 = acc;
    }
}

// ---- weight prep: 112 fragment tiles (1KB each, 32x32 layout) + plain biases ----
extern "C" __global__ void __launch_bounds__(256)
glow_prep(const float* __restrict__ s2w1, const float* __restrict__ s2w2,
          const float* __restrict__ s2w3, const float* __restrict__ s1w1,
          const float* __restrict__ s1w2, const float* __restrict__ s1w3,
          const float* __restrict__ s2b1, const float* __restrict__ s2b2,
          const float* __restrict__ s2b3, const float* __restrict__ s1b1,
          const float* __restrict__ s1b2, const float* __restrict__ s1b3,
          char* __restrict__ wsb)
{
    const int wave = threadIdx.x >> 6, lane = threadIdx.x & 63;
    const int col = lane & 31, g = lane >> 5;
    const int gw = blockIdx.x * 4 + wave;

    if (gw < 112) {
        int mlp = gw / 56, t = gw % 56;
        const float* Ws[2][3] = {{s2w1, s2w2, s2w3}, {s1w1, s1w2, s1w3}};
        const float* W; int K, row, k0;
        if (t < 8)       { W = Ws[mlp][0]; K = 32;  int ft = t >> 1, ks = t & 1;
                           row = 32 * ft + col; k0 = 16 * ks + 8 * g; }
        else if (t < 40) { int u = t - 8;  W = Ws[mlp][1]; K = 128; int ft = u >> 3, ks = u & 7;
                           row = 32 * ft + col; k0 = 16 * ks + 8 * g; }
        else             { int u = t - 40; W = Ws[mlp][2]; K = 128; int T = u >> 3, ks = u & 7;
                           row = perm3(T, col); k0 = 16 * ks + 8 * g; }
        const float* p = W + (size_t)row * K + k0;
        union U { uint4 q; bf16x8 v; } u;
        #pragma unroll
        for (int j = 0; j < 8; ++j) u.v[j] = (short)f2bf(p[j]);
        reinterpret_cast<uint4*>(wsb)[gw * 64 + lane] = u.q;
    } else if (blockIdx.x == 28) {
        const float* Bs[2][3] = {{s2b1, s2b2, s2b3}, {s1b1, s1b2, s1b3}};
        float* dst = reinterpret_cast<float*>(wsb + BIAS_OFF);
        for (int i = threadIdx.x; i < 640; i += 256) {
            int mlp = i / 320, j = i % 320;
            float v;
            if (j < 128)      v = Bs[mlp][0][j];
            else if (j < 256) v = Bs[mlp][1][j - 128];
            else              v = Bs[mlp][2][j - 256];
            dst[i] = v;
        }
    }
}

template<int MODE>
__global__ void __launch_bounds__(256, 4)
glow_main(const float* __restrict__ x,
          const float* __restrict__ s1w1, const float* __restrict__ s1b1,
          const float* __restrict__ s1w2, const float* __restrict__ s1b2,
          const float* __restrict__ s1w3, const float* __restrict__ s1b3,
          const float* __restrict__ s2w1, const float* __restrict__ s2b1,
          const float* __restrict__ s2w2, const float* __restrict__ s2b2,
          const float* __restrict__ s2w3, const float* __restrict__ s2b3,
          const char* __restrict__ wsb, float* __restrict__ out)
{
    __shared__ __align__(16) char lds[LDS_BYTES];
    char* A = lds;             // region A [64][256B]
    char* B = lds + 16384;     // region B [64][256B]
    // planes(x2)@B; MLP0: L1 B->A, L2 A->B, L3 reads B;
    // epi1 planes(y1)@A; MLP1: L1 A->B, L2 B->A, L3 reads A.

    const int tid  = threadIdx.x;
    const int w = tid >> 6, lane = tid & 63;
    const int col = lane & 31, g = lane >> 5;
    const int T3 = w & 1, rg3 = w >> 1;
    const size_t rowbase = (size_t)blockIdx.x * 64;
    const float* gx = x   + rowbase * 64;
    float*       go = out + rowbase * 64;

    const WPtrs P0 = {s2w1, s2b1, s2w2, s2b2, s2w3, s2b3};
    const WPtrs P1 = {s1w1, s1b1, s1w2, s1b2, s1w3, s1b3};

    f32x16 acc;
    f32x4 xv[2];
    const int r3 = 32 * rg3 + col;

    // ---- Phase A: pack x2 -> hi/lo planes @ B (each element ONCE) ----
    #pragma unroll
    for (int it = 0; it < 2; ++it) {
        int chunk = it * 256 + tid;          // 512 chunks of 4 floats
        int r = chunk >> 3, c4 = (chunk & 7) * 4;
        f32x4 v = *reinterpret_cast<const f32x4*>(gx + (size_t)r * 64 + 32 + c4);
        unsigned int h0 = pk2bf(v[0], v[1]), h1p = pk2bf(v[2], v[3]);
        unsigned int l0 = pk2bf(v[0] - lo16f(h0),  v[1] - hi16f(h0));
        unsigned int l1 = pk2bf(v[2] - lo16f(h1p), v[3] - hi16f(h1p));
        *reinterpret_cast<u32x2*>(B + r * 80 + 2 * c4)        = u32x2{h0, h1p};
        *reinterpret_cast<u32x2*>(B + 5120 + r * 80 + 2 * c4) = u32x2{l0, l1};
    }
    __syncthreads();                                  // (1)

    // ---- MLP s2 on x2 (barriers 2,3) ----
    run_mlp<MODE>(wsb, P0, 0, B, B + 5120, A, B, gx, xv,
                  w, g, col, lane, T3, rg3, acc);

    // ---- epilogue 1: y1 = e(s2)*x1 + t2 -> out cols 0..31 + planes @ A ----
    #pragma unroll
    for (int Q = 0; Q < 2; ++Q) {
        const int scol = 16 * T3 + 8 * Q + 4 * g;
        f32x4 y;
        #pragma unroll
        for (int jj = 0; jj < 4; ++jj)
            y[jj] = fmaf(e_fun(acc[4 * Q + jj]), xv[Q][jj], acc[8 + 4 * Q + jj]);
        *reinterpret_cast<f32x4*>(go + (size_t)r3 * 64 + scol) = y;
        unsigned int h0 = pk2bf(y[0], y[1]), h1p = pk2bf(y[2], y[3]);
        unsigned int l0 = pk2bf(y[0] - lo16f(h0),  y[1] - hi16f(h0));
        unsigned int l1 = pk2bf(y[2] - lo16f(h1p), y[3] - hi16f(h1p));
        const int po = r3 * 80 + 2 * scol;
        *reinterpret_cast<u32x2*>(A + po)        = u32x2{h0, h1p};
        *reinterpret_cast<u32x2*>(A + 5120 + po) = u32x2{l0, l1};
    }
    __syncthreads();                                  // (4)

    // ---- MLP s1 on y1 (barriers 5,6) ----
    run_mlp<MODE>(wsb, P1, 1, A, A + 5120, B, A, gx + 32, xv,
                  w, g, col, lane, T3, rg3, acc);

    // ---- epilogue 2: y2 = e(s1)*x2 + t1 -> out cols 32..63 ----
    #pragma unroll
    for (int Q = 0; Q < 2; ++Q) {
        const int scol = 16 * T3 + 8 * Q + 4 * g;
        f32x4 y;
        #pragma unroll
        for (int jj = 0; jj < 4; ++jj)
            y[jj] = fmaf(e_fun(acc[4 * Q + jj]), xv[Q][jj], acc[8 + 4 * Q + jj]);
        *reinterpret_cast<f32x4*>(go + (size_t)r3 * 64 + 32 + scol) = y;
    }
}

extern "C" void kernel_launch(void* const* d_in, const int* in_sizes, int n_in,
                              void* d_out, int out_size, void* d_ws, size_t ws_size,
                              hipStream_t stream) {
    const float* x    = (const float*)d_in[0];
    const float* s1w1 = (const float*)d_in[1];
    const float* s1b1 = (const float*)d_in[2];
    const float* s1w2 = (const float*)d_in[3];
    const float* s1b2 = (const float*)d_in[4];
    const float* s1w3 = (const float*)d_in[5];
    const float* s1b3 = (const float*)d_in[6];
    const float* s2w1 = (const float*)d_in[7];
    const float* s2b1 = (const float*)d_in[8];
    const float* s2w2 = (const float*)d_in[9];
    const float* s2b2 = (const float*)d_in[10];
    const float* s2w3 = (const float*)d_in[11];
    const float* s2b3 = (const float*)d_in[12];
    float* out = (float*)d_out;
    char* wsb  = (char*)d_ws;

    int nrows   = in_sizes[0] / 64;   // 262144
    int nblocks = nrows / 64;         // 4096

    if (ws_size >= (size_t)WS_NEED) {
        hipLaunchKernelGGL(glow_prep, dim3(29), dim3(256), 0, stream,
                           s2w1, s2w2, s2w3, s1w1, s1w2, s1w3,
                           s2b1, s2b2, s2b3, s1b1, s1b2, s1b3, wsb);
        hipLaunchKernelGGL((glow_main<1>), dim3(nblocks), dim3(256), 0, stream,
                           x, s1w1, s1b1, s1w2, s1b2, s1w3, s1b3,
                           s2w1, s2b1, s2w2, s2b2, s2w3, s2b3, wsb, out);
    } else {
        hipLaunchKernelGGL((glow_main<0>), dim3(nblocks), dim3(256), 0, stream,
                           x, s1w1, s1b1, s1w2, s1b2, s1w3, s1b3,
                           s2w1, s2b1, s2w2, s2b2, s2w3, s2b3, wsb, out);
    }
}